// Round 1
// baseline (290.108 us; speedup 1.0000x reference)
//
#include <hip/hip_runtime.h>
#include <stdint.h>

#define B_ 4
#define N_ 4096
#define Q_ 4096
#define K_ 32
#define E_ 32
#define R_ 16
#define F_ 53   // 3 rel_pos + 1 radius + 32 emb + 16 rbf + 1 dist

static constexpr int QPB = 4;          // queries (waves) per block
static constexpr int THREADS = QPB * 64;

__global__ __launch_bounds__(THREADS, 2)
void lfb_kernel(const float* __restrict__ coords,
                const int* __restrict__ atom_types,
                const float* __restrict__ radii,
                const float* __restrict__ qpts,
                const int* __restrict__ atom_mask,
                const int* __restrict__ query_mask,
                const float* __restrict__ embed,
                const float* __restrict__ centers,
                float* __restrict__ out)
{
    __shared__ float sx[N_], sy[N_], sz[N_];
    __shared__ unsigned char smk[N_];
    __shared__ __align__(16) float stage[QPB][K_ * F_];

    const int tid  = threadIdx.x;
    const int lane = tid & 63;
    const int wv   = tid >> 6;
    const int bq0  = blockIdx.x * QPB;
    const int b    = bq0 / Q_;          // all queries in a block share the batch

    // stage this batch's atom coords + mask into LDS
    for (int i = tid; i < N_; i += THREADS) {
        const float* c = coords + (size_t)(b * N_ + i) * 3;
        sx[i] = c[0];
        sy[i] = c[1];
        sz[i] = c[2];
        smk[i] = (unsigned char)(atom_mask[b * N_ + i] != 0);
    }
    __syncthreads();

    const int bq = bq0 + wv;            // flat (b,q)
    const float qx = qpts[(size_t)bq * 3 + 0];
    const float qy = qpts[(size_t)bq * 3 + 1];
    const float qz = qpts[(size_t)bq * 3 + 2];

    // distributed sorted top-K list: lane j (j<32) holds the (j+1)-th smallest key
    unsigned long long key = ~0ull;

    for (int base = 0; base < N_; base += 64) {
        const int a = base + lane;
        // bit-exact reference distance: no FMA, sequential sum, CR sqrt
        const float dx = __fsub_rn(qx, sx[a]);
        const float dy = __fsub_rn(qy, sy[a]);
        const float dz = __fsub_rn(qz, sz[a]);
        float s = __fadd_rn(__fadd_rn(__fmul_rn(dx, dx), __fmul_rn(dy, dy)),
                            __fmul_rn(dz, dz));
        s = __fadd_rn(s, 1e-12f);
        const float d = __fsqrt_rn(s);
        const unsigned int db = smk[a] ? __float_as_uint(d) : 0x7F800000u; // masked -> +inf
        unsigned long long cand = ((unsigned long long)db << 32) | (unsigned int)a;

        const unsigned long long T = __shfl(key, 31);   // current 32nd best
        unsigned long long m = __ballot(cand < T);
        while (m) {
            const int src = __ffsll(m) - 1;
            m &= m - 1;
            const unsigned long long nk = __shfl(cand, src);
            const unsigned long long up = __shfl_up(key, 1);
            if (lane < K_) {
                const unsigned long long repl =
                    (lane == 0) ? nk : (up <= nk ? nk : up);
                key = (key <= nk) ? key : repl;   // wave-parallel sorted insert
            }
        }
    }

    const size_t BQK = (size_t)B_ * Q_ * K_;
    float* out_feat = out;
    float* out_mask = out + BQK * (size_t)F_;
    float* out_idx  = out_mask + BQK;
    float* out_dist = out_idx + BQK;

    const bool qm = query_mask[bq] != 0;

    if (lane < K_) {
        const float d  = __uint_as_float((unsigned int)(key >> 32));
        const int   idx = (int)(key & 0xFFFFFFFFull);
        const bool  am = smk[idx] != 0;
        const bool  nm = am && (d <= 5.0f) && qm;

        float* f = &stage[wv][lane * F_];
        f[0] = nm ? __fsub_rn(qx, sx[idx]) : 0.0f;
        f[1] = nm ? __fsub_rn(qy, sy[idx]) : 0.0f;
        f[2] = nm ? __fsub_rn(qz, sz[idx]) : 0.0f;
        f[3] = nm ? radii[b * N_ + idx] : 0.0f;

        const int t = atom_types[b * N_ + idx];
        const float* er = embed + t * E_;
        #pragma unroll
        for (int e = 0; e < E_; ++e) f[4 + e] = nm ? er[e] : 0.0f;

        const float NG = -(float)(256.0 / 25.0);   // -RBF_GAMMA = -10.24 as f32
        #pragma unroll
        for (int r = 0; r < R_; ++r) {
            const float dd = __fsub_rn(d, centers[r]);
            const float a2 = __fmul_rn(dd, dd);
            f[36 + r] = nm ? expf(__fmul_rn(NG, a2)) : 0.0f;
        }
        f[52] = nm ? d : 0.0f;

        const size_t o = (size_t)bq * K_ + lane;
        out_mask[o] = nm ? 1.0f : 0.0f;
        out_idx[o]  = am ? (float)idx : -1.0f;
        out_dist[o] = nm ? d : 0.0f;
    }
    __syncthreads();

    // coalesced float4 copy-out of this wave's feature tile
    {
        const float4* s4 = (const float4*)stage[wv];
        float4* d4 = (float4*)(out_feat + (size_t)bq * (size_t)(K_ * F_));
        for (int t4 = lane; t4 < (K_ * F_) / 4; t4 += 64) d4[t4] = s4[t4];
    }
}

extern "C" void kernel_launch(void* const* d_in, const int* in_sizes, int n_in,
                              void* d_out, int out_size, void* d_ws, size_t ws_size,
                              hipStream_t stream) {
    const float* coords     = (const float*)d_in[0];
    const int*   atom_types = (const int*)d_in[1];
    const float* radii      = (const float*)d_in[2];
    const float* qpts       = (const float*)d_in[3];
    const int*   atom_mask  = (const int*)d_in[4];
    const int*   query_mask = (const int*)d_in[5];
    const float* embed      = (const float*)d_in[6];
    const float* centers    = (const float*)d_in[7];

    dim3 grid((B_ * Q_) / QPB);
    dim3 block(THREADS);
    lfb_kernel<<<grid, block, 0, stream>>>(coords, atom_types, radii, qpts,
                                           atom_mask, query_mask, embed, centers,
                                           (float*)d_out);
}

// Round 2
// 193.124 us; speedup vs baseline: 1.5022x; 1.5022x over previous
//
#include <hip/hip_runtime.h>
#include <stdint.h>

#define B_ 4
#define N_ 4096
#define Q_ 4096
#define K_ 32
#define E_ 32
#define R_ 16
#define F_ 53   // 3 rel_pos + 1 radius + 32 emb + 16 rbf + 1 dist

static constexpr int QPB = 4;          // queries (waves) per block
static constexpr int THREADS = QPB * 64;
static constexpr int CAP = 256;        // candidate buffer capacity per wave (u64)

__device__ __forceinline__ void bitonic_sort64_u32(unsigned int& v, int lane) {
    #pragma unroll
    for (int k = 2; k <= 64; k <<= 1) {
        #pragma unroll
        for (int j = k >> 1; j > 0; j >>= 1) {
            unsigned int o = __shfl_xor(v, j);
            const bool asc = ((lane & k) == 0);          // k==64: always asc
            const bool lower = ((lane & j) == 0);
            unsigned int mn = v < o ? v : o;
            unsigned int mx = v < o ? o : v;
            v = (lower == asc) ? mn : mx;
        }
    }
}

__device__ __forceinline__ void bitonic_sort64_u64(unsigned long long& v, int lane) {
    #pragma unroll
    for (int k = 2; k <= 64; k <<= 1) {
        #pragma unroll
        for (int j = k >> 1; j > 0; j >>= 1) {
            unsigned long long o = __shfl_xor(v, j);
            const bool asc = ((lane & k) == 0);
            const bool lower = ((lane & j) == 0);
            unsigned long long mn = v < o ? v : o;
            unsigned long long mx = v < o ? o : v;
            v = (lower == asc) ? mn : mx;
        }
    }
}

// merge sorted-asc `best` with sorted-asc `c` (both 64-wide), keep lowest 64 sorted
__device__ __forceinline__ void merge64_u64(unsigned long long& best,
                                            unsigned long long c, int lane) {
    unsigned long long rev = __shfl(c, 63 - lane);
    unsigned long long v = best < rev ? best : rev;   // half-cleaner -> bitonic
    #pragma unroll
    for (int j = 32; j > 0; j >>= 1) {
        unsigned long long o = __shfl_xor(v, j);
        const bool lower = ((lane & j) == 0);
        unsigned long long mn = v < o ? v : o;
        unsigned long long mx = v < o ? o : v;
        v = lower ? mn : mx;
    }
    best = v;
}

__global__ __launch_bounds__(THREADS, 2)
void lfb_kernel(const float* __restrict__ coords,
                const int* __restrict__ atom_types,
                const float* __restrict__ radii,
                const float* __restrict__ qpts,
                const int* __restrict__ atom_mask,
                const int* __restrict__ query_mask,
                const float* __restrict__ embed,
                const float* __restrict__ centers,
                float* __restrict__ out)
{
    __shared__ float sx[N_], sy[N_], sz[N_];
    __shared__ unsigned int smaskw[N_ / 32];
    __shared__ __align__(16) float stage[QPB][K_ * F_];  // also overlaid as cand buf

    const int tid  = threadIdx.x;
    const int lane = tid & 63;
    const int wv   = tid >> 6;
    const int bq0  = blockIdx.x * QPB;
    const int b    = bq0 / Q_;

    // stage this batch's atom coords into LDS (SoA) + packed mask bits
    for (int i = tid; i < N_; i += THREADS) {
        const float* c = coords + (size_t)(b * N_ + i) * 3;
        sx[i] = c[0];
        sy[i] = c[1];
        sz[i] = c[2];
        const bool mv = atom_mask[b * N_ + i] != 0;
        unsigned long long bm = __ballot(mv);
        if ((lane & 31) == 0)
            smaskw[i >> 5] = (unsigned int)((lane == 0) ? bm : (bm >> 32));
    }
    __syncthreads();

    const int bq = bq0 + wv;
    const float qx = qpts[(size_t)bq * 3 + 0];
    const float qy = qpts[(size_t)bq * 3 + 1];
    const float qz = qpts[(size_t)bq * 3 + 2];

    // ---------- pass 1: per-lane min distance-bits over stride-64 column ----------
    unsigned int mnb = 0xFFFFFFFFu;
    for (int i = 0; i < N_ / 64; ++i) {
        const int a = i * 64 + lane;
        const float dx = __fsub_rn(qx, sx[a]);
        const float dy = __fsub_rn(qy, sy[a]);
        const float dz = __fsub_rn(qz, sz[a]);
        float s = __fadd_rn(__fadd_rn(__fmul_rn(dx, dx), __fmul_rn(dy, dy)),
                            __fmul_rn(dz, dz));
        s = __fadd_rn(s, 1e-12f);
        const float d = __fsqrt_rn(s);
        const unsigned int w = smaskw[a >> 5];            // broadcast read
        const unsigned int db = ((w >> (a & 31)) & 1u) ? __float_as_uint(d)
                                                       : 0x7F800000u;
        mnb = mnb < db ? mnb : db;
    }
    // 32nd-smallest lane-min = guaranteed upper bound on the true 32nd distance
    bitonic_sort64_u32(mnb, lane);
    const unsigned int Tub = __shfl(mnb, 31);

    // ---------- pass 2: ballot-collect candidates <= Tub into LDS buffer ----------
    unsigned long long* cbuf = reinterpret_cast<unsigned long long*>(stage[wv]);
    const unsigned long long lt = (1ull << lane) - 1ull;
    int cnt = 0;
    for (int i = 0; i < N_ / 64; ++i) {
        const int a = i * 64 + lane;
        const float dx = __fsub_rn(qx, sx[a]);
        const float dy = __fsub_rn(qy, sy[a]);
        const float dz = __fsub_rn(qz, sz[a]);
        float s = __fadd_rn(__fadd_rn(__fmul_rn(dx, dx), __fmul_rn(dy, dy)),
                            __fmul_rn(dz, dz));
        s = __fadd_rn(s, 1e-12f);
        const float d = __fsqrt_rn(s);
        const unsigned int w = smaskw[a >> 5];
        const unsigned int db = ((w >> (a & 31)) & 1u) ? __float_as_uint(d)
                                                       : 0x7F800000u;
        const bool pass = db <= Tub;
        const unsigned long long m = __ballot(pass);
        if (pass) {
            const int slot = cnt + __popcll(m & lt);
            if (slot < CAP)
                cbuf[slot] = ((unsigned long long)db << 32) | (unsigned int)a;
        }
        cnt += __popcll(m);
    }

    unsigned long long key;   // lanes 0..31 will hold sorted top-32 keys

    if (cnt <= CAP) {
        // ---------- pass 3: exact sort of the small candidate set ----------
        unsigned long long best;
        const int nch = (cnt + 63) >> 6;
        for (int c = 0; c < nch; ++c) {
            const int slot = c * 64 + lane;
            unsigned long long v = (slot < cnt) ? cbuf[slot] : ~0ull;
            bitonic_sort64_u64(v, lane);
            if (c == 0) best = v;
            else        merge64_u64(best, v, lane);
        }
        key = best;
    } else {
        // ---------- fallback (pathological masks/ties): streaming insertion ----------
        key = ~0ull;
        for (int base = 0; base < N_; base += 64) {
            const int a = base + lane;
            const float dx = __fsub_rn(qx, sx[a]);
            const float dy = __fsub_rn(qy, sy[a]);
            const float dz = __fsub_rn(qz, sz[a]);
            float s = __fadd_rn(__fadd_rn(__fmul_rn(dx, dx), __fmul_rn(dy, dy)),
                                __fmul_rn(dz, dz));
            s = __fadd_rn(s, 1e-12f);
            const float d = __fsqrt_rn(s);
            const unsigned int w = smaskw[a >> 5];
            const unsigned int db = ((w >> (a & 31)) & 1u) ? __float_as_uint(d)
                                                           : 0x7F800000u;
            unsigned long long cand = ((unsigned long long)db << 32) | (unsigned int)a;
            const unsigned long long T = __shfl(key, 31);
            unsigned long long m = __ballot(cand < T);
            while (m) {
                const int src = __ffsll(m) - 1;
                m &= m - 1;
                const unsigned long long nk = __shfl(cand, src);
                const unsigned long long up = __shfl_up(key, 1);
                if (lane < K_) {
                    const unsigned long long repl =
                        (lane == 0) ? nk : (up <= nk ? nk : up);
                    key = (key <= nk) ? key : repl;
                }
            }
        }
    }

    // compiler barrier: cand-buffer (u64) loads above must precede float stores below
    asm volatile("" ::: "memory");

    const size_t BQK = (size_t)B_ * Q_ * K_;
    float* out_feat = out;
    float* out_mask = out + BQK * (size_t)F_;
    float* out_idx  = out_mask + BQK;
    float* out_dist = out_idx + BQK;

    const bool qm = query_mask[bq] != 0;

    if (lane < K_) {
        const float d  = __uint_as_float((unsigned int)(key >> 32));
        const int   idx = (int)(key & 0xFFFFFFFFull);
        const bool  am = ((smaskw[idx >> 5] >> (idx & 31)) & 1u) != 0;
        const bool  nm = am && (d <= 5.0f) && qm;

        float* f = &stage[wv][lane * F_];
        f[0] = nm ? __fsub_rn(qx, sx[idx]) : 0.0f;
        f[1] = nm ? __fsub_rn(qy, sy[idx]) : 0.0f;
        f[2] = nm ? __fsub_rn(qz, sz[idx]) : 0.0f;
        f[3] = nm ? radii[b * N_ + idx] : 0.0f;

        const int t = atom_types[b * N_ + idx];
        const float* er = embed + t * E_;
        #pragma unroll
        for (int e = 0; e < E_; ++e) f[4 + e] = nm ? er[e] : 0.0f;

        const float NG = -(float)(256.0 / 25.0);   // -RBF_GAMMA = -10.24
        #pragma unroll
        for (int r = 0; r < R_; ++r) {
            const float dd = __fsub_rn(d, centers[r]);
            const float a2 = __fmul_rn(dd, dd);
            f[36 + r] = nm ? expf(__fmul_rn(NG, a2)) : 0.0f;
        }
        f[52] = nm ? d : 0.0f;

        const size_t o = (size_t)bq * K_ + lane;
        out_mask[o] = nm ? 1.0f : 0.0f;
        out_idx[o]  = am ? (float)idx : -1.0f;
        out_dist[o] = nm ? d : 0.0f;
    }
    __syncthreads();

    // coalesced float4 copy-out of this wave's feature tile
    {
        const float4* s4 = (const float4*)stage[wv];
        float4* d4 = (float4*)(out_feat + (size_t)bq * (size_t)(K_ * F_));
        for (int t4 = lane; t4 < (K_ * F_) / 4; t4 += 64) d4[t4] = s4[t4];
    }
}

extern "C" void kernel_launch(void* const* d_in, const int* in_sizes, int n_in,
                              void* d_out, int out_size, void* d_ws, size_t ws_size,
                              hipStream_t stream) {
    const float* coords     = (const float*)d_in[0];
    const int*   atom_types = (const int*)d_in[1];
    const float* radii      = (const float*)d_in[2];
    const float* qpts       = (const float*)d_in[3];
    const int*   atom_mask  = (const int*)d_in[4];
    const int*   query_mask = (const int*)d_in[5];
    const float* embed      = (const float*)d_in[6];
    const float* centers    = (const float*)d_in[7];

    dim3 grid((B_ * Q_) / QPB);
    dim3 block(THREADS);
    lfb_kernel<<<grid, block, 0, stream>>>(coords, atom_types, radii, qpts,
                                           atom_mask, query_mask, embed, centers,
                                           (float*)d_out);
}

// Round 3
// 113.693 us; speedup vs baseline: 2.5517x; 1.6986x over previous
//
#include <hip/hip_runtime.h>
#include <stdint.h>

#define B_ 4
#define N_ 4096
#define Q_ 4096
#define K_ 32
#define E_ 32
#define R_ 16
#define F_ 53   // 3 rel_pos + 1 radius + 32 emb + 16 rbf + 1 dist

static constexpr int QPB = 16;         // queries (waves) per block
static constexpr int THREADS = QPB * 64;
static constexpr int CAP = 256;        // candidate buffer capacity per wave (u64)

__device__ __forceinline__ void bitonic_sort64_u32(unsigned int& v, int lane) {
    #pragma unroll
    for (int k = 2; k <= 64; k <<= 1) {
        #pragma unroll
        for (int j = k >> 1; j > 0; j >>= 1) {
            unsigned int o = __shfl_xor(v, j);
            const bool asc = ((lane & k) == 0);          // k==64: always asc
            const bool lower = ((lane & j) == 0);
            unsigned int mn = v < o ? v : o;
            unsigned int mx = v < o ? o : v;
            v = (lower == asc) ? mn : mx;
        }
    }
}

__device__ __forceinline__ void bitonic_sort64_u64(unsigned long long& v, int lane) {
    #pragma unroll
    for (int k = 2; k <= 64; k <<= 1) {
        #pragma unroll
        for (int j = k >> 1; j > 0; j >>= 1) {
            unsigned long long o = __shfl_xor(v, j);
            const bool asc = ((lane & k) == 0);
            const bool lower = ((lane & j) == 0);
            unsigned long long mn = v < o ? v : o;
            unsigned long long mx = v < o ? o : v;
            v = (lower == asc) ? mn : mx;
        }
    }
}

// merge sorted-asc `best` with sorted-asc `c` (both 64-wide), keep lowest 64 sorted
__device__ __forceinline__ void merge64_u64(unsigned long long& best,
                                            unsigned long long c, int lane) {
    unsigned long long rev = __shfl(c, 63 - lane);
    unsigned long long v = best < rev ? best : rev;   // half-cleaner -> bitonic
    #pragma unroll
    for (int j = 32; j > 0; j >>= 1) {
        unsigned long long o = __shfl_xor(v, j);
        const bool lower = ((lane & j) == 0);
        unsigned long long mn = v < o ? v : o;
        unsigned long long mx = v < o ? o : v;
        v = lower ? mn : mx;
    }
    best = v;
}

__global__ __launch_bounds__(THREADS, 4)
void lfb_kernel(const float* __restrict__ coords,
                const int* __restrict__ atom_types,
                const float* __restrict__ radii,
                const float* __restrict__ qpts,
                const int* __restrict__ atom_mask,
                const int* __restrict__ query_mask,
                const float* __restrict__ embed,
                const float* __restrict__ centers,
                float* __restrict__ out)
{
    __shared__ __align__(16) float sx[N_], sy[N_], sz[N_];
    __shared__ unsigned int smaskw[N_ / 32];
    __shared__ __align__(16) float stage[QPB][K_ * F_];  // also overlaid as cand buf

    const int tid  = threadIdx.x;
    const int lane = tid & 63;
    const int wv   = tid >> 6;
    const int bq0  = blockIdx.x * QPB;
    const int b    = bq0 / Q_;          // Q_ % QPB == 0: one batch per block

    // stage this batch's atom coords into LDS (SoA) + packed mask bits
    for (int i = tid; i < N_; i += THREADS) {
        const float* c = coords + (size_t)(b * N_ + i) * 3;
        sx[i] = c[0];
        sy[i] = c[1];
        sz[i] = c[2];
        const bool mv = atom_mask[b * N_ + i] != 0;
        unsigned long long bm = __ballot(mv);
        if ((lane & 31) == 0)
            smaskw[i >> 5] = (unsigned int)((lane == 0) ? bm : (bm >> 32));
    }
    __syncthreads();

    const int bq = bq0 + wv;
    const float qx = qpts[(size_t)bq * 3 + 0];
    const float qy = qpts[(size_t)bq * 3 + 1];
    const float qz = qpts[(size_t)bq * 3 + 2];

    // ---------- pass 1: per-lane min of squared-dist bits (no sqrt), 4 atoms/lane ----------
    unsigned int mnb = 0xFFFFFFFFu;
    #pragma unroll 2
    for (int i = 0; i < N_ / 256; ++i) {
        const int a0 = i * 256 + lane * 4;
        const float4 X = *(const float4*)&sx[a0];
        const float4 Y = *(const float4*)&sy[a0];
        const float4 Z = *(const float4*)&sz[a0];
        const unsigned int w = smaskw[a0 >> 5] >> (a0 & 31);  // 4 mask bits at lsb
        #pragma unroll
        for (int j = 0; j < 4; ++j) {
            const float cx = j == 0 ? X.x : j == 1 ? X.y : j == 2 ? X.z : X.w;
            const float cy = j == 0 ? Y.x : j == 1 ? Y.y : j == 2 ? Y.z : Y.w;
            const float cz = j == 0 ? Z.x : j == 1 ? Z.y : j == 2 ? Z.z : Z.w;
            const float dx = __fsub_rn(qx, cx);
            const float dy = __fsub_rn(qy, cy);
            const float dz = __fsub_rn(qz, cz);
            float s = __fadd_rn(__fadd_rn(__fmul_rn(dx, dx), __fmul_rn(dy, dy)),
                                __fmul_rn(dz, dz));
            s = __fadd_rn(s, 1e-12f);
            const unsigned int sb = ((w >> j) & 1u) ? __float_as_uint(s)
                                                    : 0x7F800000u;
            mnb = mnb < sb ? mnb : sb;
        }
    }
    // 32nd-smallest lane-min (on s) -> exact d-bits upper bound via monotone sqrt
    bitonic_sort64_u32(mnb, lane);
    const unsigned int Tub_s = __shfl(mnb, 31);
    const unsigned int Tdb = __float_as_uint(__fsqrt_rn(__uint_as_float(Tub_s)));

    // ---------- pass 2: collect all atoms with d-bits <= Tdb (order-free buffer) ----------
    unsigned long long* cbuf = reinterpret_cast<unsigned long long*>(stage[wv]);
    const unsigned long long lt = (1ull << lane) - 1ull;
    int cnt = 0;
    for (int i = 0; i < N_ / 256; ++i) {
        const int a0 = i * 256 + lane * 4;
        const float4 X = *(const float4*)&sx[a0];
        const float4 Y = *(const float4*)&sy[a0];
        const float4 Z = *(const float4*)&sz[a0];
        const unsigned int w = smaskw[a0 >> 5] >> (a0 & 31);
        #pragma unroll
        for (int j = 0; j < 4; ++j) {
            const float cx = j == 0 ? X.x : j == 1 ? X.y : j == 2 ? X.z : X.w;
            const float cy = j == 0 ? Y.x : j == 1 ? Y.y : j == 2 ? Y.z : Y.w;
            const float cz = j == 0 ? Z.x : j == 1 ? Z.y : j == 2 ? Z.z : Z.w;
            const float dx = __fsub_rn(qx, cx);
            const float dy = __fsub_rn(qy, cy);
            const float dz = __fsub_rn(qz, cz);
            float s = __fadd_rn(__fadd_rn(__fmul_rn(dx, dx), __fmul_rn(dy, dy)),
                                __fmul_rn(dz, dz));
            s = __fadd_rn(s, 1e-12f);
            const float d = __fsqrt_rn(s);
            const unsigned int db = ((w >> j) & 1u) ? __float_as_uint(d)
                                                    : 0x7F800000u;
            const bool pass = db <= Tdb;
            const unsigned long long m = __ballot(pass);
            if (pass) {
                const int slot = cnt + __popcll(m & lt);
                if (slot < CAP)
                    cbuf[slot] = ((unsigned long long)db << 32)
                               | (unsigned int)(a0 + j);
            }
            cnt += __popcll(m);
        }
    }

    unsigned long long key;   // lanes 0..31 will hold sorted top-32 keys

    if (cnt <= CAP) {
        // ---------- pass 3: exact sort of the small candidate set ----------
        unsigned long long best;
        const int nch = (cnt + 63) >> 6;
        for (int c = 0; c < nch; ++c) {
            const int slot = c * 64 + lane;
            unsigned long long v = (slot < cnt) ? cbuf[slot] : ~0ull;
            bitonic_sort64_u64(v, lane);
            if (c == 0) best = v;
            else        merge64_u64(best, v, lane);
        }
        key = best;
    } else {
        // ---------- fallback (pathological masks/ties): streaming insertion ----------
        key = ~0ull;
        for (int base = 0; base < N_; base += 64) {
            const int a = base + lane;
            const float dx = __fsub_rn(qx, sx[a]);
            const float dy = __fsub_rn(qy, sy[a]);
            const float dz = __fsub_rn(qz, sz[a]);
            float s = __fadd_rn(__fadd_rn(__fmul_rn(dx, dx), __fmul_rn(dy, dy)),
                                __fmul_rn(dz, dz));
            s = __fadd_rn(s, 1e-12f);
            const float d = __fsqrt_rn(s);
            const unsigned int w = smaskw[a >> 5];
            const unsigned int db = ((w >> (a & 31)) & 1u) ? __float_as_uint(d)
                                                           : 0x7F800000u;
            unsigned long long cand = ((unsigned long long)db << 32) | (unsigned int)a;
            const unsigned long long T = __shfl(key, 31);
            unsigned long long m = __ballot(cand < T);
            while (m) {
                const int src = __ffsll(m) - 1;
                m &= m - 1;
                const unsigned long long nk = __shfl(cand, src);
                const unsigned long long up = __shfl_up(key, 1);
                if (lane < K_) {
                    const unsigned long long repl =
                        (lane == 0) ? nk : (up <= nk ? nk : up);
                    key = (key <= nk) ? key : repl;
                }
            }
        }
    }

    // compiler barrier: cand-buffer (u64) loads above must precede float stores below
    asm volatile("" ::: "memory");

    const size_t BQK = (size_t)B_ * Q_ * K_;
    float* out_feat = out;
    float* out_mask = out + BQK * (size_t)F_;
    float* out_idx  = out_mask + BQK;
    float* out_dist = out_idx + BQK;

    const bool qm = query_mask[bq] != 0;

    if (lane < K_) {
        const float d  = __uint_as_float((unsigned int)(key >> 32));
        const int   idx = (int)(key & 0xFFFFFFFFull);
        const bool  am = ((smaskw[idx >> 5] >> (idx & 31)) & 1u) != 0;
        const bool  nm = am && (d <= 5.0f) && qm;

        float* f = &stage[wv][lane * F_];
        f[0] = nm ? __fsub_rn(qx, sx[idx]) : 0.0f;
        f[1] = nm ? __fsub_rn(qy, sy[idx]) : 0.0f;
        f[2] = nm ? __fsub_rn(qz, sz[idx]) : 0.0f;
        f[3] = nm ? radii[b * N_ + idx] : 0.0f;

        const int t = atom_types[b * N_ + idx];
        const float4* er4 = (const float4*)(embed + t * E_);
        #pragma unroll
        for (int e = 0; e < E_ / 4; ++e) {
            const float4 v = er4[e];
            f[4 + e * 4 + 0] = nm ? v.x : 0.0f;
            f[4 + e * 4 + 1] = nm ? v.y : 0.0f;
            f[4 + e * 4 + 2] = nm ? v.z : 0.0f;
            f[4 + e * 4 + 3] = nm ? v.w : 0.0f;
        }

        const float NG = -(float)(256.0 / 25.0);   // -RBF_GAMMA = -10.24
        #pragma unroll
        for (int r = 0; r < R_; ++r) {
            const float dd = __fsub_rn(d, centers[r]);
            const float a2 = __fmul_rn(dd, dd);
            f[36 + r] = nm ? expf(__fmul_rn(NG, a2)) : 0.0f;
        }
        f[52] = nm ? d : 0.0f;

        const size_t o = (size_t)bq * K_ + lane;
        out_mask[o] = nm ? 1.0f : 0.0f;
        out_idx[o]  = am ? (float)idx : -1.0f;
        out_dist[o] = nm ? d : 0.0f;
    }
    __syncthreads();

    // coalesced float4 copy-out of this wave's feature tile
    {
        const float4* s4 = (const float4*)stage[wv];
        float4* d4 = (float4*)(out_feat + (size_t)bq * (size_t)(K_ * F_));
        for (int t4 = lane; t4 < (K_ * F_) / 4; t4 += 64) d4[t4] = s4[t4];
    }
}

extern "C" void kernel_launch(void* const* d_in, const int* in_sizes, int n_in,
                              void* d_out, int out_size, void* d_ws, size_t ws_size,
                              hipStream_t stream) {
    const float* coords     = (const float*)d_in[0];
    const int*   atom_types = (const int*)d_in[1];
    const float* radii      = (const float*)d_in[2];
    const float* qpts       = (const float*)d_in[3];
    const int*   atom_mask  = (const int*)d_in[4];
    const int*   query_mask = (const int*)d_in[5];
    const float* embed      = (const float*)d_in[6];
    const float* centers    = (const float*)d_in[7];

    dim3 grid((B_ * Q_) / QPB);
    dim3 block(THREADS);
    lfb_kernel<<<grid, block, 0, stream>>>(coords, atom_types, radii, qpts,
                                           atom_mask, query_mask, embed, centers,
                                           (float*)d_out);
}

// Round 4
// 62.841 us; speedup vs baseline: 4.6165x; 1.8092x over previous
//
#include <hip/hip_runtime.h>
#include <stdint.h>

#define B_ 4
#define N_ 4096
#define Q_ 4096
#define K_ 32
#define E_ 32
#define R_ 16
#define F_ 53   // 3 rel_pos + 1 radius + 32 emb + 16 rbf + 1 dist

static constexpr int QPB = 16;         // queries (waves) per block
static constexpr int THREADS = QPB * 64;
static constexpr int CAP = 208;        // candidate capacity per wave (u64)
static constexpr int TILE = K_ * F_;   // 1696 floats per query tile
static constexpr int NSLOT = 4;        // stage slots shared by QPB waves
static constexpr int POOLB = (QPB * CAP * 8 > NSLOT * TILE * 4)
                           ? (QPB * CAP * 8) : (NSLOT * TILE * 4);

__device__ __forceinline__ unsigned int s2bits(float qx, float qy, float qz,
                                               float cx, float cy, float cz) {
    // bit-exact reference ordering: no FMA, fixed association, NO eps here
    const float dx = __fsub_rn(qx, cx);
    const float dy = __fsub_rn(qy, cy);
    const float dz = __fsub_rn(qz, cz);
    return __float_as_uint(
        __fadd_rn(__fadd_rn(__fmul_rn(dx, dx), __fmul_rn(dy, dy)),
                  __fmul_rn(dz, dz)));
}

__device__ __forceinline__ void bitonic_sort64_u32(unsigned int& v, int lane) {
    #pragma unroll
    for (int k = 2; k <= 64; k <<= 1) {
        #pragma unroll
        for (int j = k >> 1; j > 0; j >>= 1) {
            unsigned int o = __shfl_xor(v, j);
            const bool asc = ((lane & k) == 0);
            const bool lower = ((lane & j) == 0);
            unsigned int mn = v < o ? v : o;
            unsigned int mx = v < o ? o : v;
            v = (lower == asc) ? mn : mx;
        }
    }
}

__device__ __forceinline__ void bitonic_sort64_u64(unsigned long long& v, int lane) {
    #pragma unroll
    for (int k = 2; k <= 64; k <<= 1) {
        #pragma unroll
        for (int j = k >> 1; j > 0; j >>= 1) {
            unsigned long long o = __shfl_xor(v, j);
            const bool asc = ((lane & k) == 0);
            const bool lower = ((lane & j) == 0);
            unsigned long long mn = v < o ? v : o;
            unsigned long long mx = v < o ? o : v;
            v = (lower == asc) ? mn : mx;
        }
    }
}

// merge sorted-asc `best` with sorted-asc `c` (both 64-wide), keep lowest 64 sorted
__device__ __forceinline__ void merge64_u64(unsigned long long& best,
                                            unsigned long long c, int lane) {
    unsigned long long rev = __shfl(c, 63 - lane);
    unsigned long long v = best < rev ? best : rev;
    #pragma unroll
    for (int j = 32; j > 0; j >>= 1) {
        unsigned long long o = __shfl_xor(v, j);
        const bool lower = ((lane & j) == 0);
        unsigned long long mn = v < o ? v : o;
        unsigned long long mx = v < o ? o : v;
        v = lower ? mn : mx;
    }
    best = v;
}

__global__ __launch_bounds__(THREADS, 8)
void lfb_kernel(const float* __restrict__ coords,
                const int* __restrict__ atom_types,
                const float* __restrict__ radii,
                const float* __restrict__ qpts,
                const int* __restrict__ atom_mask,
                const int* __restrict__ query_mask,
                const float* __restrict__ embed,
                const float* __restrict__ centers,
                float* __restrict__ out)
{
    __shared__ __align__(16) float sx[N_], sy[N_], sz[N_];
    __shared__ unsigned int smaskw[N_ / 32];
    __shared__ __align__(16) unsigned char pool[POOLB]; // cand bufs / stage slots

    const int tid  = threadIdx.x;
    const int lane = tid & 63;
    const int wv   = tid >> 6;
    const int bq0  = blockIdx.x * QPB;
    const int b    = bq0 / Q_;

    // stage coords (masked atoms poisoned to 1e30 -> d == +inf exactly) + mask bits
    for (int i = tid; i < N_; i += THREADS) {
        const float* c = coords + (size_t)(b * N_ + i) * 3;
        const bool mv = atom_mask[b * N_ + i] != 0;
        sx[i] = mv ? c[0] : 1e30f;
        sy[i] = mv ? c[1] : 1e30f;
        sz[i] = mv ? c[2] : 1e30f;
        unsigned long long bm = __ballot(mv);
        if ((lane & 31) == 0)
            smaskw[i >> 5] = (unsigned int)((lane == 0) ? bm : (bm >> 32));
    }
    __syncthreads();

    const int bq = bq0 + wv;
    const float qx = qpts[(size_t)bq * 3 + 0];
    const float qy = qpts[(size_t)bq * 3 + 1];
    const float qz = qpts[(size_t)bq * 3 + 2];

    // ---- pass 1: per-lane min of raw squared-dist bits (no eps, no sqrt) ----
    unsigned int mnb = 0xFFFFFFFFu;
    for (int i = 0; i < N_ / 256; ++i) {
        const int a0 = i * 256 + lane * 4;
        const float4 X = *(const float4*)&sx[a0];
        const float4 Y = *(const float4*)&sy[a0];
        const float4 Z = *(const float4*)&sz[a0];
        const unsigned int s0 = s2bits(qx, qy, qz, X.x, Y.x, Z.x);
        const unsigned int s1 = s2bits(qx, qy, qz, X.y, Y.y, Z.y);
        const unsigned int s2 = s2bits(qx, qy, qz, X.z, Y.z, Z.z);
        const unsigned int s3 = s2bits(qx, qy, qz, X.w, Y.w, Z.w);
        const unsigned int m01 = s0 < s1 ? s0 : s1;
        const unsigned int m23 = s2 < s3 ? s2 : s3;
        const unsigned int m = m01 < m23 ? m01 : m23;
        mnb = mnb < m ? mnb : m;
    }
    // 32nd-smallest lane-min Ts bounds the true 32nd distance; convert to a
    // conservative s-bits threshold ST covering every atom with d <= dT.
    bitonic_sort64_u32(mnb, lane);
    const unsigned int Ts = __shfl(mnb, 31);
    const float dT = __fsqrt_rn(__fadd_rn(__uint_as_float(Ts), 1e-12f));
    const float u = __uint_as_float(__float_as_uint(dT) + 1);  // next float up
    unsigned int ST = __float_as_uint(__fmul_rn(u, u)) + 2;
    ST = ST < Ts ? Ts : ST;   // guarantee the 32 witness atoms are collected

    // ---- pass 2: collect atoms with s_bits <= ST (no sqrt in hot loop) ----
    unsigned long long* cbuf = reinterpret_cast<unsigned long long*>(pool) + wv * CAP;
    const unsigned long long lt = (1ull << lane) - 1ull;
    int cnt = 0;
    for (int i = 0; i < N_ / 256; ++i) {
        const int a0 = i * 256 + lane * 4;
        const float4 X = *(const float4*)&sx[a0];
        const float4 Y = *(const float4*)&sy[a0];
        const float4 Z = *(const float4*)&sz[a0];
        unsigned int sb[4];
        sb[0] = s2bits(qx, qy, qz, X.x, Y.x, Z.x);
        sb[1] = s2bits(qx, qy, qz, X.y, Y.y, Z.y);
        sb[2] = s2bits(qx, qy, qz, X.z, Y.z, Z.z);
        sb[3] = s2bits(qx, qy, qz, X.w, Y.w, Z.w);
        #pragma unroll
        for (int j = 0; j < 4; ++j) {
            const bool pass = sb[j] <= ST;
            const unsigned long long m = __ballot(pass);
            if (pass) {
                const int slot = cnt + __popcll(m & lt);
                if (slot < CAP)
                    cbuf[slot] = ((unsigned long long)sb[j] << 32)
                               | (unsigned int)(a0 + j);
            }
            cnt += __popcll(m);
        }
    }

    unsigned long long key;   // lanes 0..31 will hold sorted top-32 (d_bits, idx)

    if (cnt <= CAP) {
        // ---- pass 3: exact (d_bits, idx) sort of the small candidate set ----
        unsigned long long best;
        const int nch = (cnt + 63) >> 6;
        for (int c = 0; c < nch; ++c) {
            const int slot = c * 64 + lane;
            unsigned long long v = ~0ull;
            if (slot < cnt) {
                const unsigned long long raw = cbuf[slot];
                const float s = __uint_as_float((unsigned int)(raw >> 32));
                const float d = __fsqrt_rn(__fadd_rn(s, 1e-12f)); // exact ref path
                v = ((unsigned long long)__float_as_uint(d) << 32)
                  | (unsigned int)(raw & 0xFFFFFFFFull);
            }
            bitonic_sort64_u64(v, lane);
            if (c == 0) best = v;
            else        merge64_u64(best, v, lane);
        }
        key = best;
    } else {
        // ---- fallback (pathological masks/ties): streaming insertion ----
        key = ~0ull;
        for (int base = 0; base < N_; base += 64) {
            const int a = base + lane;
            const unsigned int sb = s2bits(qx, qy, qz, sx[a], sy[a], sz[a]);
            const float d = __fsqrt_rn(__fadd_rn(__uint_as_float(sb), 1e-12f));
            unsigned long long cand =
                ((unsigned long long)__float_as_uint(d) << 32) | (unsigned int)a;
            const unsigned long long T = __shfl(key, 31);
            unsigned long long m = __ballot(cand < T);
            while (m) {
                const int src = __ffsll(m) - 1;
                m &= m - 1;
                const unsigned long long nk = __shfl(cand, src);
                const unsigned long long up = __shfl_up(key, 1);
                if (lane < K_) {
                    const unsigned long long repl =
                        (lane == 0) ? nk : (up <= nk ? nk : up);
                    key = (key <= nk) ? key : repl;
                }
            }
        }
    }

    const size_t BQK = (size_t)B_ * Q_ * K_;
    float* out_feat = out;
    float* out_mask = out + BQK * (size_t)F_;
    float* out_idx  = out_mask + BQK;
    float* out_dist = out_idx + BQK;

    const bool qm = query_mask[bq] != 0;

    const float d_l  = __uint_as_float((unsigned int)(key >> 32));
    const int   id_l = (int)(key & 0xFFFFFFFFull);
    const bool  am_l = ((smaskw[(id_l & (N_ - 1)) >> 5] >> (id_l & 31)) & 1u) != 0;
    const bool  nm_l = am_l && (d_l <= 5.0f) && qm;

    // scalar outputs don't need the stage pool: write before the rounds
    if (lane < K_) {
        const size_t o = (size_t)bq * K_ + lane;
        out_mask[o] = nm_l ? 1.0f : 0.0f;
        out_idx[o]  = am_l ? (float)id_l : -1.0f;
        out_dist[o] = nm_l ? d_l : 0.0f;
    }

    __syncthreads();   // all cand-buffer reads done before stage overlay

    // ---- feature build: NSLOT stage slots time-shared in QPB/NSLOT rounds ----
    float* slot = reinterpret_cast<float*>(pool) + (wv & (NSLOT - 1)) * TILE;
    for (int r = 0; r < QPB / NSLOT; ++r) {
        if ((wv >> 2) == r) {
            if (lane < K_) {
                float* f = slot + lane * F_;
                f[0] = nm_l ? __fsub_rn(qx, sx[id_l]) : 0.0f;
                f[1] = nm_l ? __fsub_rn(qy, sy[id_l]) : 0.0f;
                f[2] = nm_l ? __fsub_rn(qz, sz[id_l]) : 0.0f;
                f[3] = nm_l ? radii[b * N_ + id_l] : 0.0f;

                const int t = atom_types[b * N_ + id_l];
                const float4* er4 = (const float4*)(embed + t * E_);
                #pragma unroll
                for (int e = 0; e < E_ / 4; ++e) {
                    const float4 v = er4[e];
                    f[4 + e * 4 + 0] = nm_l ? v.x : 0.0f;
                    f[4 + e * 4 + 1] = nm_l ? v.y : 0.0f;
                    f[4 + e * 4 + 2] = nm_l ? v.z : 0.0f;
                    f[4 + e * 4 + 3] = nm_l ? v.w : 0.0f;
                }

                const float NG = -(float)(256.0 / 25.0);   // -RBF_GAMMA
                #pragma unroll
                for (int rr = 0; rr < R_; ++rr) {
                    const float dd = __fsub_rn(d_l, centers[rr]);
                    const float a2 = __fmul_rn(dd, dd);
                    f[36 + rr] = nm_l ? expf(__fmul_rn(NG, a2)) : 0.0f;
                }
                f[52] = nm_l ? d_l : 0.0f;
            }
            // coalesced float4 copy-out (same wave: LDS in-order, no barrier needed)
            const float4* s4 = (const float4*)slot;
            float4* d4 = (float4*)(out_feat + (size_t)bq * (size_t)TILE);
            for (int t4 = lane; t4 < TILE / 4; t4 += 64) d4[t4] = s4[t4];
        }
        __syncthreads();
    }
}

extern "C" void kernel_launch(void* const* d_in, const int* in_sizes, int n_in,
                              void* d_out, int out_size, void* d_ws, size_t ws_size,
                              hipStream_t stream) {
    const float* coords     = (const float*)d_in[0];
    const int*   atom_types = (const int*)d_in[1];
    const float* radii      = (const float*)d_in[2];
    const float* qpts       = (const float*)d_in[3];
    const int*   atom_mask  = (const int*)d_in[4];
    const int*   query_mask = (const int*)d_in[5];
    const float* embed      = (const float*)d_in[6];
    const float* centers    = (const float*)d_in[7];

    dim3 grid((B_ * Q_) / QPB);
    dim3 block(THREADS);
    lfb_kernel<<<grid, block, 0, stream>>>(coords, atom_types, radii, qpts,
                                           atom_mask, query_mask, embed, centers,
                                           (float*)d_out);
}